// Round 11
// baseline (337.598 us; speedup 1.0000x reference)
//
#include <hip/hip_runtime.h>
#include <hip/hip_bf16.h>

#define Bq 8
#define Tq 4096
#define Cq 192
#define NHq 24
#define HSq 8
#define Mq (Bq * Tq)   // 32768

#define CLq 64              // WKV chunk length
#define NCHq (Tq / CLq)     // 64 chunks
#define TSq 32              // LDS tile steps inside a chunk

typedef short short8 __attribute__((ext_vector_type(8)));
typedef float f32x4 __attribute__((ext_vector_type(4)));

__device__ __forceinline__ unsigned short f2bf(float f) {
    union { float f; unsigned u; } v; v.f = f;
    unsigned u = v.u;
    return (unsigned short)((u + 0x7FFFu + ((u >> 16) & 1u)) >> 16);
}
__device__ __forceinline__ float bf2f(unsigned short u) {
    union { unsigned u; float f; } v; v.u = (unsigned)u << 16;
    return v.f;
}
__device__ __forceinline__ float4 bf4_to_f4(ushort4 u) {
    return make_float4(bf2f(u.x), bf2f(u.y), bf2f(u.z), bf2f(u.w));
}

// ---------------------------------------------------------------------------
// fold lp/hd/vd/cd convs into one effective 3x3 kernel, bf16 [N=cout][K]
// ---------------------------------------------------------------------------
__global__ void prep_weights_kernel(const float* __restrict__ w_lp,
                                    const float* __restrict__ w_hd,
                                    const float* __restrict__ w_vd,
                                    const float* __restrict__ w_cd,
                                    const float* __restrict__ theta,
                                    unsigned short* __restrict__ Wg) {
    int idx = blockIdx.x * 256 + threadIdx.x;   // cout*192 + cin
    if (idx >= Cq * Cq) return;
    int cout = idx / Cq, cin = idx - cout * Cq;
    float t9[9];
#pragma unroll
    for (int t = 0; t < 9; ++t) t9[t] = 0.f;
    float lp = w_lp[idx];
    t9[1] += lp; t9[3] += lp; t9[5] += lp; t9[7] += lp; t9[4] -= 4.f * lp;
    float h0 = w_hd[idx * 3 + 0], h1 = w_hd[idx * 3 + 1], h2 = w_hd[idx * 3 + 2];
    t9[0] += h0; t9[3] += h1; t9[6] += h2;
    t9[2] -= h0; t9[5] -= h1; t9[8] -= h2;
    float v0 = w_vd[idx * 3 + 0], v1 = w_vd[idx * 3 + 1], v2 = w_vd[idx * 3 + 2];
    t9[0] += v0; t9[1] += v1; t9[2] += v2;
    t9[6] -= v0; t9[7] -= v1; t9[8] -= v2;
    float sum = 0.f;
#pragma unroll
    for (int t = 0; t < 9; ++t) {
        float cdv = w_cd[idx * 9 + t];
        t9[t] += cdv; sum += cdv;
    }
    t9[4] -= theta[0] * sum;
#pragma unroll
    for (int t = 0; t < 9; ++t)
        Wg[(size_t)cout * 1728 + t * Cq + cin] = f2bf(t9[t]);
}

// ---------------------------------------------------------------------------
// all other weight transposes/conversions in ONE launch
// ---------------------------------------------------------------------------
__global__ __launch_bounds__(256) void prep_pack_kernel(
    const float* __restrict__ maa_w1, const float* __restrict__ Wr,
    const float* __restrict__ Wk, const float* __restrict__ Wv,
    const float* __restrict__ Wgp, const float* __restrict__ Wo,
    const float* __restrict__ maa_w2, const float* __restrict__ d1,
    const float* __restrict__ d2,
    unsigned short* __restrict__ Wt_maa, unsigned short* __restrict__ Wt_r,
    unsigned short* __restrict__ Wt_k, unsigned short* __restrict__ Wt_v,
    unsigned short* __restrict__ Wt_g, unsigned short* __restrict__ Wt_o,
    unsigned short* __restrict__ w2t, unsigned short* __restrict__ Wt_d1,
    unsigned short* __restrict__ Wt_d2) {
    int idx = blockIdx.x * 256 + threadIdx.x;
    if (idx < 30720) {                       // maa_w1 [192][160] -> [160][192]
        int n = idx / 192, k = idx - n * 192;
        Wt_maa[idx] = f2bf(maa_w1[(size_t)k * 160 + n]);
        return;
    }
    idx -= 30720;
    if (idx < 5 * 36864) {                   // 5 square weights -> [N][K]
        int s = idx / 36864, e = idx - s * 36864;
        int n = e / 192, k = e - n * 192;
        const float* W = s == 0 ? Wr : s == 1 ? Wk : s == 2 ? Wv : s == 3 ? Wgp : Wo;
        unsigned short* D = s == 0 ? Wt_r : s == 1 ? Wt_k : s == 2 ? Wt_v : s == 3 ? Wt_g : Wt_o;
        D[e] = f2bf(W[(size_t)k * 192 + n]);
        return;
    }
    idx -= 5 * 36864;
    if (idx < 30720) {                       // w2 [5][32][192] -> [5][192][32]
        int f = idx / 6144, rem = idx - f * 6144;
        int n = rem >> 5, k = rem & 31;
        w2t[idx] = f2bf(maa_w2[(size_t)(f * 32 + k) * 192 + n]);
        return;
    }
    idx -= 30720;
    if (idx < 12288) {                       // d1 [192][64] -> [64][192]
        int n = idx / 192, k = idx - n * 192;
        Wt_d1[idx] = f2bf(d1[(size_t)k * 64 + n]);
        return;
    }
    idx -= 12288;
    if (idx < 12288) {                       // d2 [64][192] -> [192][64]
        int n = idx / 64, k = idx - n * 64;
        Wt_d2[idx] = f2bf(d2[(size_t)k * 192 + n]);
    }
}

// x [B,4096,192] fp32 -> x_halo [B][66][66][192] bf16, zero borders
__global__ __launch_bounds__(256) void halo_kernel(
    const float* __restrict__ x, unsigned short* __restrict__ xh) {
    int idx = blockIdx.x * 256 + threadIdx.x;
    int c4 = (idx % 48) * 4;
    int cell = idx / 48;
    int hx = cell % 66;
    int rest = cell / 66;
    int hy = rest % 66;
    int bb = rest / 66;
    ushort4 o = make_ushort4(0, 0, 0, 0);
    if (hy >= 1 && hy <= 64 && hx >= 1 && hx <= 64) {
        size_t g = ((size_t)(bb << 12) + (hy - 1) * 64 + (hx - 1)) * Cq + c4;
        float4 v = *(const float4*)&x[g];
        o = make_ushort4(f2bf(v.x), f2bf(v.y), f2bf(v.z), f2bf(v.w));
    }
    *(ushort4*)&xh[(size_t)cell * Cq + c4] = o;
}

// ---------------------------------------------------------------------------
// bf16 MFMA GEMM: C[M][N] = A @ Wt^T, Wt bf16 [N][K].
// A fragments loaded DIRECTLY global->VGPR (per-wave-private; no LDS stage).
// Only B goes through LDS (shared across the 4 waves).
// ALOAD: 3 = plain bf16 A [M][K]; 1 = conv implicit-gemm from x_halo
// EPI: 0 none, 2 tanh, 4 exp(-exp(aux0[n]+acc)),
//      5 conv dual-out: xx=acc-x_halo -> Cb, xxx=x+xx*maa_x -> C2 (both bf16)
// OBF16: 1 = store bf16. tile 128x64xK64, 4 waves, wave = 32 rows x 64 cols
// ---------------------------------------------------------------------------
#define GBM 128
#define GBK 64

template <int ALOAD, int EPI, int OBF16>
__global__ __launch_bounds__(256) void mgemm_kernel(
    const unsigned short* __restrict__ Asrc,
    const unsigned short* __restrict__ Wt,
    void* __restrict__ Cv, int N, int K,
    const float* __restrict__ aux0,
    const unsigned short* __restrict__ xh,
    unsigned short* __restrict__ C2) {
    __shared__ unsigned char Blds[64 * GBK * 2];
    float* C = (float*)Cv;
    unsigned short* Cb = (unsigned short*)Cv;

    const int tid = threadIdx.x;
    const int wid = tid >> 6, lane = tid & 63;
    const int llo = lane & 15, lhi = lane >> 4;
    const int m0 = blockIdx.x * GBM, n0 = blockIdx.y * 64;

    f32x4 acc[2][4];
#pragma unroll
    for (int a = 0; a < 2; ++a)
#pragma unroll
        for (int b = 0; b < 4; ++b) {
            f32x4 z = {0.f, 0.f, 0.f, 0.f};
            acc[a][b] = z;
        }

    for (int k0 = 0; k0 < K; k0 += GBK) {
        __syncthreads();
        // ---- stage B (64x64 bf16): 2 chunks/thread ----
#pragma unroll
        for (int rep = 0; rep < 2; ++rep) {
            int c = tid + rep * 256;
            int row = c >> 3, kseg = c & 7;
            int n = n0 + row;
            short8 val = {0, 0, 0, 0, 0, 0, 0, 0};
            if (n < N) val = *(const short8*)&Wt[(size_t)n * K + k0 + kseg * 8];
            *(short8*)(Blds + row * 128 + ((kseg * 16) ^ ((row & 7) << 4))) = val;
        }
        // ---- A fragments direct from global (issue before barrier) ----
        short8 af[2][2];   // [mf][kc]
#pragma unroll
        for (int mf = 0; mf < 2; ++mf) {
            int row = m0 + wid * 32 + mf * 16 + llo;
            size_t base;
            if (ALOAD == 3) {
                base = (size_t)row * K + k0;
            } else {  // conv: tap uniform per K-step (64 | 192)
                int tap = k0 / Cq;
                int cinb = k0 - tap * Cq;
                int t3 = tap / 3;
                int bb = row >> 12, pos = row & 4095;
                int hy = (pos >> 6) + t3;
                int hx = (pos & 63) + tap - t3 * 3;
                base = ((size_t)bb * 4356 + hy * 66 + hx) * Cq + cinb;
            }
#pragma unroll
            for (int kc = 0; kc < 2; ++kc)
                af[mf][kc] = *(const short8*)&Asrc[base + kc * 32 + lhi * 8];
        }
        __syncthreads();
        // ---- MFMA: 2 k-chunks of 32, 2x4 frags ----
#pragma unroll
        for (int kc = 0; kc < 2; ++kc) {
            int kb = kc * 64 + lhi * 16;
            short8 bq[4];
#pragma unroll
            for (int nf = 0; nf < 4; ++nf) {
                int row = nf * 16 + llo;
                bq[nf] = *(const short8*)(Blds + row * 128 + (kb ^ ((row & 7) << 4)));
            }
#pragma unroll
            for (int mf = 0; mf < 2; ++mf)
#pragma unroll
                for (int nf = 0; nf < 4; ++nf)
                    acc[mf][nf] = __builtin_amdgcn_mfma_f32_16x16x32_bf16(
                        af[mf][kc], bq[nf], acc[mf][nf], 0, 0, 0);
        }
    }
    // ---- epilogue: C/D layout col(lane&15)=n, row(lhi*4+r)=m ----
    if (EPI == 5) {
#pragma unroll
        for (int mf = 0; mf < 2; ++mf)
#pragma unroll
            for (int nf = 0; nf < 4; ++nf) {
                int n = n0 + nf * 16 + llo;
#pragma unroll
                for (int r = 0; r < 4; ++r) {
                    int m = m0 + wid * 32 + mf * 16 + lhi * 4 + r;
                    int pos = m & 4095, bb = m >> 12;
                    size_t cell = (size_t)bb * 4356 + ((pos >> 6) + 1) * 66 + (pos & 63) + 1;
                    float xv = bf2f(xh[cell * Cq + n]);
                    float xxv = acc[mf][nf][r] - xv;
                    Cb[(size_t)m * Cq + n] = f2bf(xxv);
                    C2[(size_t)m * Cq + n] = f2bf(fmaf(xxv, aux0[n], xv));
                }
            }
        return;
    }
#pragma unroll
    for (int mf = 0; mf < 2; ++mf) {
#pragma unroll
        for (int nf = 0; nf < 4; ++nf) {
            int n = n0 + nf * 16 + llo;
            if (n >= N) continue;
#pragma unroll
            for (int r = 0; r < 4; ++r) {
                int m = m0 + wid * 32 + mf * 16 + lhi * 4 + r;
                float val = acc[mf][nf][r];
                if (EPI == 2) val = tanhf(val);
                else if (EPI == 4) val = expf(-expf(aux0[n] + val));
                if (OBF16) Cb[(size_t)m * N + n] = f2bf(val);
                else C[(size_t)m * N + n] = val;
            }
        }
    }
}

// ---------------------------------------------------------------------------
// proj4: 4 projections (v, r, k, g=silu) in one launch; blockIdx.z selects.
// A direct global->VGPR; B via LDS. K=N=192, bf16 out.
// ---------------------------------------------------------------------------
__global__ __launch_bounds__(256) void proj4_kernel(
    const unsigned short* __restrict__ A0, const unsigned short* __restrict__ A1,
    const unsigned short* __restrict__ A2, const unsigned short* __restrict__ A3,
    const unsigned short* __restrict__ W0, const unsigned short* __restrict__ W1,
    const unsigned short* __restrict__ W2, const unsigned short* __restrict__ W3,
    unsigned short* __restrict__ O0, unsigned short* __restrict__ O1,
    unsigned short* __restrict__ O2, unsigned short* __restrict__ O3) {
    __shared__ unsigned char Blds[64 * GBK * 2];
    const int z = blockIdx.z;
    const unsigned short* Asrc = z == 0 ? A0 : z == 1 ? A1 : z == 2 ? A2 : A3;
    const unsigned short* Wt = z == 0 ? W0 : z == 1 ? W1 : z == 2 ? W2 : W3;
    unsigned short* Cb = z == 0 ? O0 : z == 1 ? O1 : z == 2 ? O2 : O3;
    const bool silu = (z == 3);

    const int tid = threadIdx.x;
    const int wid = tid >> 6, lane = tid & 63;
    const int llo = lane & 15, lhi = lane >> 4;
    const int m0 = blockIdx.x * GBM, n0 = blockIdx.y * 64;

    f32x4 acc[2][4];
#pragma unroll
    for (int a = 0; a < 2; ++a)
#pragma unroll
        for (int b = 0; b < 4; ++b) {
            f32x4 zz = {0.f, 0.f, 0.f, 0.f};
            acc[a][b] = zz;
        }

    for (int k0 = 0; k0 < Cq; k0 += GBK) {
        __syncthreads();
#pragma unroll
        for (int rep = 0; rep < 2; ++rep) {
            int c = tid + rep * 256;
            int row = c >> 3, kseg = c & 7;
            short8 val = *(const short8*)&Wt[(size_t)(n0 + row) * Cq + k0 + kseg * 8];
            *(short8*)(Blds + row * 128 + ((kseg * 16) ^ ((row & 7) << 4))) = val;
        }
        short8 af[2][2];
#pragma unroll
        for (int mf = 0; mf < 2; ++mf) {
            size_t base = (size_t)(m0 + wid * 32 + mf * 16 + llo) * Cq + k0;
#pragma unroll
            for (int kc = 0; kc < 2; ++kc)
                af[mf][kc] = *(const short8*)&Asrc[base + kc * 32 + lhi * 8];
        }
        __syncthreads();
#pragma unroll
        for (int kc = 0; kc < 2; ++kc) {
            int kb = kc * 64 + lhi * 16;
            short8 bq[4];
#pragma unroll
            for (int nf = 0; nf < 4; ++nf) {
                int row = nf * 16 + llo;
                bq[nf] = *(const short8*)(Blds + row * 128 + (kb ^ ((row & 7) << 4)));
            }
#pragma unroll
            for (int mf = 0; mf < 2; ++mf)
#pragma unroll
                for (int nf = 0; nf < 4; ++nf)
                    acc[mf][nf] = __builtin_amdgcn_mfma_f32_16x16x32_bf16(
                        af[mf][kc], bq[nf], acc[mf][nf], 0, 0, 0);
        }
    }
#pragma unroll
    for (int mf = 0; mf < 2; ++mf)
#pragma unroll
        for (int nf = 0; nf < 4; ++nf) {
            int n = n0 + nf * 16 + llo;
#pragma unroll
            for (int r = 0; r < 4; ++r) {
                int m = m0 + wid * 32 + mf * 16 + lhi * 4 + r;
                float val = acc[mf][nf][r];
                if (silu) val = val / (1.f + expf(-val));
                Cb[(size_t)m * Cq + n] = f2bf(val);
            }
        }
}

// ---------------------------------------------------------------------------
// mix5: operand-swapped MFMA + LDS-restaged coalesced stores.
// grid (Mq/64, 3), 128 threads (2 waves x 32 rows x 64 cols).
// ---------------------------------------------------------------------------
#define MLDW 72   // padded row (ushorts): 144 B, 16B-aligned, bank-spread
__global__ __launch_bounds__(128) void mix5_kernel(
    const unsigned short* __restrict__ xh,
    const unsigned short* __restrict__ xxb,
    const unsigned short* __restrict__ tmp_bf,
    const unsigned short* __restrict__ w2t,
    const float* __restrict__ maa_w, const float* __restrict__ maa_k,
    const float* __restrict__ maa_v, const float* __restrict__ maa_r,
    const float* __restrict__ maa_g,
    unsigned short* __restrict__ xw, unsigned short* __restrict__ xr,
    unsigned short* __restrict__ xk, unsigned short* __restrict__ xv,
    unsigned short* __restrict__ xg) {
    __shared__ unsigned short tile[2][5][16][MLDW];
    const int tid = threadIdx.x;
    const int wid = tid >> 6, lane = tid & 63;
    const int llo = lane & 15, lhi = lane >> 4;
    const int mb = blockIdx.x * 64 + wid * 32;    // 32 rows per wave
    const int nb = blockIdx.y * 64;               // 64 cols per block

    short8 aw[5][4];
#pragma unroll
    for (int f = 0; f < 5; ++f)
#pragma unroll
        for (int nf = 0; nf < 4; ++nf)
            aw[f][nf] = *(const short8*)&w2t[((size_t)f * Cq + nb + nf * 16 + llo) * 32 + lhi * 8];

    unsigned short* const outs[5] = {xw, xk, xv, xr, xg};

#pragma unroll
    for (int sub = 0; sub < 2; ++sub) {
        short8 bt[5];
        {
            const unsigned short* trow = &tmp_bf[(size_t)(mb + sub * 16 + llo) * 160 + lhi * 8];
#pragma unroll
            for (int f = 0; f < 5; ++f) bt[f] = *(const short8*)&trow[f * 32];
        }
        int m = mb + sub * 16 + llo;
        int pos = m & 4095, bb = m >> 12;
        size_t xbase = ((size_t)bb * 4356 + ((pos >> 6) + 1) * 66 + (pos & 63) + 1) * Cq;
#pragma unroll
        for (int nf = 0; nf < 4; ++nf) {
            f32x4 acc[5];
#pragma unroll
            for (int f = 0; f < 5; ++f) {
                f32x4 z = {0.f, 0.f, 0.f, 0.f};
                acc[f] = __builtin_amdgcn_mfma_f32_16x16x32_bf16(aw[f][nf], bt[f], z, 0, 0, 0);
            }
            int n0 = nb + nf * 16 + lhi * 4;
            size_t g = (size_t)m * Cq + n0;
            float4 xv4 = bf4_to_f4(*(const ushort4*)&xh[xbase + n0]);
            float4 xx4 = bf4_to_f4(*(const ushort4*)&xxb[g]);
            float4 mw4 = *(const float4*)&maa_w[n0];
            float4 mk4 = *(const float4*)&maa_k[n0];
            float4 mv4 = *(const float4*)&maa_v[n0];
            float4 mr4 = *(const float4*)&maa_r[n0];
            float4 mg4 = *(const float4*)&maa_g[n0];
            float xvv[4] = {xv4.x, xv4.y, xv4.z, xv4.w};
            float xxv[4] = {xx4.x, xx4.y, xx4.z, xx4.w};
            float mwv[4] = {mw4.x, mw4.y, mw4.z, mw4.w};
            float mkv[4] = {mk4.x, mk4.y, mk4.z, mk4.w};
            float mvv[4] = {mv4.x, mv4.y, mv4.z, mv4.w};
            float mrv[4] = {mr4.x, mr4.y, mr4.z, mr4.w};
            float mgv[4] = {mg4.x, mg4.y, mg4.z, mg4.w};
            ushort4 ov[5];
#pragma unroll
            for (int r = 0; r < 4; ++r) {
                ((unsigned short*)&ov[0])[r] = f2bf(fmaf(xxv[r], mwv[r] + acc[0][r], xvv[r]));
                ((unsigned short*)&ov[1])[r] = f2bf(fmaf(xxv[r], mkv[r] + acc[1][r], xvv[r]));
                ((unsigned short*)&ov[2])[r] = f2bf(fmaf(xxv[r], mvv[r] + acc[2][r], xvv[r]));
                ((unsigned short*)&ov[3])[r] = f2bf(fmaf(xxv[r], mrv[r] + acc[3][r], xvv[r]));
                ((unsigned short*)&ov[4])[r] = f2bf(fmaf(xxv[r], mgv[r] + acc[4][r], xvv[r]));
            }
            int col = nf * 16 + lhi * 4;
#pragma unroll
            for (int f = 0; f < 5; ++f)
                *(ushort4*)&tile[wid][f][llo][col] = ov[f];
        }
        // restaged coalesced stores: 8 lanes cover one 128B row segment
        int row16 = lane >> 3;          // 0..7
        int colc = (lane & 7) * 8;      // ushort offset, 16B chunks
#pragma unroll
        for (int f = 0; f < 5; ++f) {
#pragma unroll
            for (int p = 0; p < 2; ++p) {
                int rr = p * 8 + row16;
                int gm = mb + sub * 16 + rr;
                *(short8*)&outs[f][(size_t)gm * Cq + nb + colc] =
                    *(const short8*)&tile[wid][f][rr][colc];
            }
        }
    }
}

// ---------------------------------------------------------------------------
// WKV6 chunked scan: lane = slot*8+i, 8 heads/wave.
// k,v,r staged in LDS as bf16 (lossless; they are bf16 in global); d fp32.
// ---------------------------------------------------------------------------
__global__ __launch_bounds__(64) void wkv_pass1_kernel(
    const unsigned short* __restrict__ k, const unsigned short* __restrict__ v,
    const float* __restrict__ d,
    float* __restrict__ Dbuf, float* __restrict__ Cbuf) {
    int chunk = blockIdx.x, hg = blockIdx.y, b = blockIdx.z;
    int lane = threadIdx.x;
    int slot = lane >> 3, i = lane & 7;
    int cbase = hg * 64;
    size_t gbase = ((size_t)b * Tq + (size_t)chunk * CLq) * Cq + cbase;
    __shared__ unsigned short ks[TSq][64], vs[TSq][64];
    __shared__ float ds[TSq][64];
    float S[8], D[8];
#pragma unroll
    for (int j = 0; j < 8; ++j) { S[j] = 0.f; D[j] = 1.f; }
    for (int t0 = 0; t0 < CLq; t0 += TSq) {
        int f = lane & 15, r4 = lane >> 4;
#pragma unroll
        for (int p = 0; p < 8; ++p) {
            int row = r4 + p * 4;
            size_t g = gbase + (size_t)(t0 + row) * Cq + f * 4;
            *(ushort4*)&ks[row][f * 4] = *(const ushort4*)&k[g];
            *(ushort4*)&vs[row][f * 4] = *(const ushort4*)&v[g];
            *(float4*)&ds[row][f * 4] = *(const float4*)&d[g];
        }
        __syncthreads();
#pragma unroll 8
        for (int t = 0; t < TSq; ++t) {
            float vv = bf2f(vs[t][lane]);
            short8 k8 = *(const short8*)&ks[t][slot * 8];
            float4 da = *(const float4*)&ds[t][slot * 8];
            float4 db = *(const float4*)&ds[t][slot * 8 + 4];
            float dd[8] = {da.x, da.y, da.z, da.w, db.x, db.y, db.z, db.w};
#pragma unroll
            for (int j = 0; j < 8; ++j) {
                float kv = bf2f((unsigned short)k8[j]) * vv;
                S[j] = fmaf(dd[j], S[j], kv);
                D[j] *= dd[j];
            }
        }
        __syncthreads();
    }
    size_t dbase = (((size_t)b * NCHq + chunk) * NHq + hg * 8) * 8;
    Dbuf[dbase + lane] = D[i];
    size_t cb = (((size_t)b * NCHq + chunk) * NHq + (hg * 8 + slot)) * 64 + i;
#pragma unroll
    for (int j = 0; j < 8; ++j) Cbuf[cb + j * 8] = S[j];
}

__global__ __launch_bounds__(64) void wkv_pass2_kernel(
    const float* __restrict__ Dbuf, const float* __restrict__ Cbuf,
    float* __restrict__ Sbuf) {
    int bh = blockIdx.x;
    int lane = threadIdx.x;
    int j = lane >> 3, i = lane & 7;
    int b = bh / NHq, h = bh - b * NHq;
    float S = 0.f;
    size_t stride = (size_t)NHq * 64;
    size_t base = ((size_t)b * NCHq * NHq + h) * 64 + j * 8 + i;
    size_t dstride = (size_t)NHq * 8;
    size_t dbase = ((size_t)b * NCHq * NHq + h) * 8 + j;
#pragma unroll 4
    for (int c = 0; c < NCHq; ++c) {
        Sbuf[base + c * stride] = S;
        float D = Dbuf[dbase + c * dstride];
        float C = Cbuf[base + c * stride];
        S = fmaf(D, S, C);
    }
}

__global__ __launch_bounds__(64) void wkv_pass3_kernel(
    const unsigned short* __restrict__ r, const unsigned short* __restrict__ k,
    const unsigned short* __restrict__ v, const float* __restrict__ d,
    const float* __restrict__ u, const float* __restrict__ Sbuf,
    unsigned short* __restrict__ y) {
    int chunk = blockIdx.x, hg = blockIdx.y, b = blockIdx.z;
    int lane = threadIdx.x;
    int slot = lane >> 3, i = lane & 7;
    int h = hg * 8 + slot;
    int cbase = hg * 64;
    size_t gbase = ((size_t)b * Tq + (size_t)chunk * CLq) * Cq + cbase;
    __shared__ unsigned short rs[TSq][64], ks[TSq][64], vs[TSq][64];
    __shared__ float ds[TSq][64];
    float S[8], uu[8];
    size_t sb = (((size_t)b * NCHq + chunk) * NHq + h) * 64 + i;
#pragma unroll
    for (int j = 0; j < 8; ++j) {
        S[j] = Sbuf[sb + j * 8];
        uu[j] = u[h * 8 + j];
    }
    for (int t0 = 0; t0 < CLq; t0 += TSq) {
        int f = lane & 15, r4 = lane >> 4;
#pragma unroll
        for (int p = 0; p < 8; ++p) {
            int row = r4 + p * 4;
            size_t g = gbase + (size_t)(t0 + row) * Cq + f * 4;
            *(ushort4*)&rs[row][f * 4] = *(const ushort4*)&r[g];
            *(ushort4*)&ks[row][f * 4] = *(const ushort4*)&k[g];
            *(ushort4*)&vs[row][f * 4] = *(const ushort4*)&v[g];
            *(float4*)&ds[row][f * 4] = *(const float4*)&d[g];
        }
        __syncthreads();
#pragma unroll 8
        for (int t = 0; t < TSq; ++t) {
            float vv = bf2f(vs[t][lane]);
            short8 r8 = *(const short8*)&rs[t][slot * 8];
            short8 k8 = *(const short8*)&ks[t][slot * 8];
            float4 da = *(const float4*)&ds[t][slot * 8];
            float4 db = *(const float4*)&ds[t][slot * 8 + 4];
            float dd[8] = {da.x, da.y, da.z, da.w, db.x, db.y, db.z, db.w};
            float yv = 0.f;
#pragma unroll
            for (int j = 0; j < 8; ++j) {
                float kv = bf2f((unsigned short)k8[j]) * vv;
                yv = fmaf(bf2f((unsigned short)r8[j]), fmaf(uu[j], kv, S[j]), yv);
                S[j] = fmaf(dd[j], S[j], kv);
            }
            y[gbase + (size_t)(t0 + t) * Cq + lane] = f2bf(yv);
        }
        __syncthreads();
    }
}

// ---------------------------------------------------------------------------
// LayerNorm + gate (y, g bf16 in) -> bf16 out
// ---------------------------------------------------------------------------
__global__ __launch_bounds__(256) void ln_gate_kernel(
    const unsigned short* __restrict__ y, const unsigned short* __restrict__ g,
    const float* __restrict__ ln_g, const float* __restrict__ ln_b,
    unsigned short* __restrict__ out) {
    int row = blockIdx.x * 4 + (threadIdx.x >> 6);
    int lane = threadIdx.x & 63;
    const unsigned short* yr = y + (size_t)row * Cq;
    float a0 = bf2f(yr[lane]), a1 = bf2f(yr[lane + 64]), a2 = bf2f(yr[lane + 128]);
    float s = a0 + a1 + a2;
    float ss = a0 * a0 + a1 * a1 + a2 * a2;
#pragma unroll
    for (int m = 1; m < 64; m <<= 1) {
        s += __shfl_xor(s, m);
        ss += __shfl_xor(ss, m);
    }
    float mu = s * (1.f / 192.f);
    float var = ss * (1.f / 192.f) - mu * mu;
    float rstd = rsqrtf(var + 1e-5f);
    const unsigned short* gr = g + (size_t)row * Cq;
    unsigned short* orow = out + (size_t)row * Cq;
    float aa[3] = {a0, a1, a2};
#pragma unroll
    for (int q = 0; q < 3; ++q) {
        int cc = lane + q * 64;
        float yn = (aa[q] - mu) * rstd * ln_g[cc] + ln_b[cc];
        orow[cc] = f2bf(yn * bf2f(gr[cc]));
    }
}

// ---------------------------------------------------------------------------
extern "C" void kernel_launch(void* const* d_in, const int* in_sizes, int n_in,
                              void* d_out, int out_size, void* d_ws, size_t ws_size,
                              hipStream_t stream) {
    const float* x        = (const float*)d_in[0];
    const float* maa_x    = (const float*)d_in[1];
    const float* maa_w    = (const float*)d_in[2];
    const float* maa_k    = (const float*)d_in[3];
    const float* maa_v    = (const float*)d_in[4];
    const float* maa_r    = (const float*)d_in[5];
    const float* maa_g    = (const float*)d_in[6];
    const float* maa_w1   = (const float*)d_in[7];
    const float* maa_w2   = (const float*)d_in[8];
    const float* decay_w1 = (const float*)d_in[9];
    const float* decay_w2 = (const float*)d_in[10];
    const float* sdecay   = (const float*)d_in[11];
    const float* u        = (const float*)d_in[12];
    const float* Wr       = (const float*)d_in[13];
    const float* Wk       = (const float*)d_in[14];
    const float* Wv       = (const float*)d_in[15];
    const float* Wgp      = (const float*)d_in[16];
    const float* Wo       = (const float*)d_in[17];
    const float* ln_g     = (const float*)d_in[18];
    const float* ln_b     = (const float*)d_in[19];
    const float* w_lp     = (const float*)d_in[20];
    const float* w_hd     = (const float*)d_in[21];
    const float* w_vd     = (const float*)d_in[22];
    const float* w_cd     = (const float*)d_in[23];
    const float* theta    = (const float*)d_in[24];
    float* out = (float*)d_out;

    const size_t BIG = (size_t)Mq * Cq;          // 6,291,456 floats
    float* ws = (float*)d_ws;
    unsigned short* Wgt_conv = (unsigned short*)ws;            // 192*1728
    unsigned short* Wt_maa = Wgt_conv + (size_t)Cq * 1728;     // 160*192
    unsigned short* Wt_r = Wt_maa + 160 * Cq;
    unsigned short* Wt_k = Wt_r + Cq * Cq;
    unsigned short* Wt_v = Wt_k + Cq * Cq;
    unsigned short* Wt_g = Wt_v + Cq * Cq;
    unsigned short* Wt_o = Wt_g + Cq * Cq;
    unsigned short* w2t  = Wt_o + Cq * Cq;                     // 5*192*32
    unsigned short* Wt_d1 = w2t + 5 * 192 * 32;                // 64*192
    unsigned short* Wt_d2 = Wt_d1 + 64 * Cq;                   // 192*64
    float* tmp  = ws + 331776;                  // M*160 region
    float* wtmp = tmp + (size_t)Mq * 160;       // M*64
    float* buf0 = wtmp + (size_t)Mq * 64;
    float* buf1 = buf0 + BIG;
    float* buf2 = buf1 + BIG;
    float* buf3 = buf2 + BIG;
    float* buf4 = buf3 + BIG;
    float* buf5 = buf4 + BIG;

    // tmp region: bf16 tmp (M*80 floats) then WKV scan scratch
    unsigned short* tmp_bf = (unsigned short*)tmp;
    float* Dbuf = tmp + (size_t)Mq * 80;
    float* Cbuf = Dbuf + (size_t)Bq * NCHq * NHq * 8;
    float* Sbuf = Cbuf + (size_t)Bq * NCHq * NHq * 64;

    // overlays (bf16 halves of fp32 buffers); lifetimes annotated:
    unsigned short* x_halo = (unsigned short*)buf1;            // halo..mix5
    unsigned short* y_b    = (unsigned short*)buf1;            // pass3..ln (front half)
    unsigned short* k_b    = (unsigned short*)(buf1 + BIG / 2); // proj4..pass3 (back half)
    unsigned short* xx_b   = (unsigned short*)buf0;            // conv..mix5
    unsigned short* xw_b   = (unsigned short*)(buf0 + BIG / 2); // mix5..decay1
    unsigned short* r_b    = (unsigned short*)buf0;            // proj4..pass3 (xx dead)
    unsigned short* xxx_b  = (unsigned short*)(buf2 + BIG / 2); // conv..maa
    unsigned short* xg_b   = xxx_b;                            // mix5..proj4
    unsigned short* xv_b   = (unsigned short*)buf2;            // mix5..proj4
    unsigned short* gate_b = (unsigned short*)buf2;            // ln..Wo (xv dead)
    unsigned short* v_b    = (unsigned short*)buf3;            // proj4..pass3
    unsigned short* g_b    = (unsigned short*)buf4;            // proj4..ln
    unsigned short* xr_b   = (unsigned short*)buf5;            // mix5..proj4
    unsigned short* xk_b   = (unsigned short*)(buf5 + BIG / 2); // mix5..proj4
    float* d_f             = buf5;                             // decay2..pass3 (fp32)
    unsigned short* wtmp_b = (unsigned short*)wtmp;            // decay mid [M][64]

    dim3 blk(256);
    const unsigned short* nosrc = nullptr;
    unsigned short* nodst = nullptr;

    // 1) weight prep (2 launches)
    prep_weights_kernel<<<dim3(144), blk, 0, stream>>>(w_lp, w_hd, w_vd, w_cd, theta, Wgt_conv);
    prep_pack_kernel<<<dim3(1056), blk, 0, stream>>>(
        maa_w1, Wr, Wk, Wv, Wgp, Wo, maa_w2, decay_w1, decay_w2,
        Wt_maa, Wt_r, Wt_k, Wt_v, Wt_g, Wt_o, w2t, Wt_d1, Wt_d2);
    // 2) halo-pad x; conv implicit GEMM (A-direct), dual-out xx_b + xxx_b
    halo_kernel<<<dim3(8 * 66 * 66 * 48 / 256), blk, 0, stream>>>(x, x_halo);
    mgemm_kernel<1, 5, 1><<<dim3(Mq / GBM, 3), blk, 0, stream>>>(
        x_halo, Wgt_conv, xx_b, Cq, 1728, maa_x, x_halo, xxx_b);
    // 3) tmp_bf = bf16(tanh(xxx @ maa_w1)) [M,160]
    mgemm_kernel<3, 2, 1><<<dim3(Mq / GBM, 3), blk, 0, stream>>>(
        xxx_b, Wt_maa, tmp_bf, 160, Cq, nullptr, nosrc, nodst);
    // 4) fused mixes: all five bf16, LDS-restaged stores
    mix5_kernel<<<dim3(Mq / 64, 3), dim3(128), 0, stream>>>(
        x_halo, xx_b, tmp_bf, w2t, maa_w, maa_k, maa_v, maa_r, maa_g,
        xw_b, xr_b, xk_b, xv_b, xg_b);
    // 5) merged projections: z = {v, r, k, g=silu}
    proj4_kernel<<<dim3(Mq / GBM, 3, 4), blk, 0, stream>>>(
        xv_b, xr_b, xk_b, xg_b,
        Wt_v, Wt_r, Wt_k, Wt_g,
        v_b, r_b, k_b, g_b);
    // 6) decay: wtmp_b = bf16(tanh(xw@w1)); d = exp(-exp(sd+.@w2)) fp32
    mgemm_kernel<3, 2, 1><<<dim3(Mq / GBM, 1), blk, 0, stream>>>(
        xw_b, Wt_d1, wtmp_b, 64, Cq, nullptr, nosrc, nodst);
    mgemm_kernel<3, 4, 0><<<dim3(Mq / GBM, 3), blk, 0, stream>>>(
        wtmp_b, Wt_d2, d_f, Cq, 64, sdecay, nosrc, nodst);
    // 7) WKV chunked scan (k,v,r bf16; d fp32) -> y_b bf16
    wkv_pass1_kernel<<<dim3(NCHq, 3, Bq), dim3(64), 0, stream>>>(k_b, v_b, d_f, Dbuf, Cbuf);
    wkv_pass2_kernel<<<dim3(Bq * NHq), dim3(64), 0, stream>>>(Dbuf, Cbuf, Sbuf);
    wkv_pass3_kernel<<<dim3(NCHq, 3, Bq), dim3(64), 0, stream>>>(r_b, k_b, v_b, d_f, u, Sbuf, y_b);
    // 8) LN + gate -> gate_b bf16
    ln_gate_kernel<<<dim3(Mq / 4), blk, 0, stream>>>(y_b, g_b, ln_g, ln_b, gate_b);
    // 9) output projection (fp32 out)
    mgemm_kernel<3, 0, 0><<<dim3(Mq / GBM, 3), blk, 0, stream>>>(
        gate_b, Wt_o, out, Cq, Cq, nullptr, nosrc, nodst);
}